// Round 11
// baseline (456.136 us; speedup 1.0000x reference)
//
#include <hip/hip_runtime.h>

#define NN 100000
#define NE 200000
#define MT (NN + NE)
#define ECAP 16   // in-degree cap; dst ~ Poisson(2); R10 passed => dataset fits

typedef unsigned short u16;
typedef unsigned int u32;
typedef __attribute__((ext_vector_type(8))) short bf16x8;
typedef __attribute__((ext_vector_type(4))) float f32x4;

__device__ __forceinline__ float bf2f(u16 u) {
    union { u32 i; float f; } v; v.i = ((u32)u) << 16; return v.f;
}
__device__ __forceinline__ u16 f2bf(float f) {
    union { u32 i; float f; } v; v.f = f;
    u32 r = v.i + 0x7fffu + ((v.i >> 16) & 1u);
    return (u16)(r >> 16);
}
__device__ __forceinline__ void unpack2(u32 u, float& lo, float& hi) {
    union { u32 i; float f; } a, b;
    a.i = u << 16; b.i = u & 0xffff0000u;
    lo = a.f; hi = b.f;
}
__device__ __forceinline__ u32 pack2(float a, float b) {
    return (u32)f2bf(a) | ((u32)f2bf(b) << 16);
}

// Inputs are fp32 (proven: R1/R5/R6 bf16-read NaN'd; R7 flag-adaptive passed
// with f32 path). All dtype branches hardcoded out.

// Build MFMA B-operand fragments (bf16) and summed f32 biases.
// Feature interleave: matrix m (of 5) -> blocks (2m, 2m+1);
// feature f = 2*(lane&15) + (b&1), k = (lane>>4)*8 + j.
// x side m: [theta_x | theta_deg | theta_r0 | theta_r1 | gamma_x]
// y side m: [gamma_y | gamma_deg | gamma_r0 | gamma_r1 | theta_y]
__global__ __launch_bounds__(256) void prep_kernel(
    const float* txw, const float* tdw, const float* tyw,
    const float* gyw, const float* gdw, const float* gxw,
    const float* trw, const float* grw,
    const float* txb, const float* tdb, const float* tyb,
    const float* gyb, const float* gdb, const float* gxb,
    const float* trb, const float* grb,
    u16* Bfx, u16* Bfy, float* bx, float* by)
{
    int t = blockIdx.x * 256 + threadIdx.x;
    if (t < 10240) {
        int side = t / 5120;
        int e = t - side * 5120;
        int b = e >> 9, lane = (e >> 3) & 63, j = e & 7;
        int m = b >> 1;
        int k = ((lane >> 4) << 3) + j;
        int f = ((lane & 15) << 1) | (b & 1);
        int idx = k * 32 + f;
        float v;
        if (side == 0) {
            v = (m == 0) ? txw[idx] : (m == 1) ? tdw[idx] : (m == 2) ? trw[idx]
              : (m == 3) ? trw[1024 + idx] : gxw[idx];
            Bfx[e] = f2bf(v);
        } else {
            v = (m == 0) ? gyw[idx] : (m == 1) ? gdw[idx] : (m == 2) ? grw[idx]
              : (m == 3) ? grw[1024 + idx] : tyw[idx];
            Bfy[e] = f2bf(v);
        }
    } else if (t < 10304) {
        int f = t - 10240;
        if (f < 32) {
            bx[f] = txb[f] + tdb[f] + tyb[f] + trb[f] + trb[32 + f];
        } else {
            f -= 32;
            by[f] = gyb[f] + gdb[f] + gxb[f] + grb[f] + grb[32 + f];
        }
    }
}

// Merged MFMA GEMM (x blocks 0..1562, y blocks 1563..4687): per wave 16 rows
// x 160 cols in 10 mfma_f32_16x16x32_bf16; aligned-LDS-transpose epilogue.
__global__ __launch_bounds__(256, 4) void gemm2(
    const float* __restrict__ x, const float* __restrict__ y,
    const u16* __restrict__ Bfx, const u16* __restrict__ Bfy,
    const float* __restrict__ bx, const float* __restrict__ by,
    const float* __restrict__ deg_g, const float* __restrict__ deg_lg,
    u16* __restrict__ Xself, u16* __restrict__ Xt,
    u16* __restrict__ Xtt,   u16* __restrict__ Xaux,
    u16* __restrict__ Yself, u16* __restrict__ Yt,
    u16* __restrict__ Ytt,   u16* __restrict__ Yaux)
{
    __shared__ __align__(16) u16 sbuf[4][4][512];   // [wave][array][16r x 32c]
    int lane = threadIdx.x & 63;
    int wib  = threadIdx.x >> 6;
    bool is_y = (blockIdx.x >= 1563);
    int wid = (is_y ? (int)blockIdx.x - 1563 : (int)blockIdx.x) * 4 + wib;
    int nwaves = is_y ? 12500 : 6250;
    if (wid >= nwaves) return;
    int r0 = wid * 16;

    const float* feat = is_y ? y : x;
    const u16* Bf     = is_y ? Bfy : Bfx;
    const float* bias = is_y ? by : bx;
    const float* deg  = is_y ? deg_lg : deg_g;
    u16 *Self = is_y ? Yself : Xself, *T = is_y ? Yt : Xt;
    u16 *TT = is_y ? Ytt : Xtt, *Aux = is_y ? Yaux : Xaux;

    // A fragment: lane holds A[m=lane&15][k=(lane>>4)*8 + j].
    union { u16 s[8]; bf16x8 v; } au;
    {
        const float4* fp = (const float4*)(feat
            + (size_t)(r0 + (lane & 15)) * 32 + ((lane >> 4) << 3));
        float4 A0 = fp[0], A1 = fp[1];
        au.s[0] = f2bf(A0.x); au.s[1] = f2bf(A0.y);
        au.s[2] = f2bf(A0.z); au.s[3] = f2bf(A0.w);
        au.s[4] = f2bf(A1.x); au.s[5] = f2bf(A1.y);
        au.s[6] = f2bf(A1.z); au.s[7] = f2bf(A1.w);
    }
    f32x4 acc[10];
    const u16* bp = Bf + lane * 8;
#pragma unroll
    for (int b = 0; b < 10; ++b) {
        bf16x8 bfr = *(const bf16x8*)(bp + b * 512);
        f32x4 z = {0.f, 0.f, 0.f, 0.f};
        acc[b] = __builtin_amdgcn_mfma_f32_16x16x32_bf16(au.v, bfr, z, 0, 0, 0);
    }

    // D layout: col = lane&15, row = (lane>>4)*4 + i; features (2n, 2n+1).
    int n = lane & 15, quad = lane >> 4;
    int rowb = r0 + quad * 4;
    float bev = bias[2 * n], bov = bias[2 * n + 1];

#pragma unroll
    for (int i = 0; i < 4; ++i) {
        float dgi = deg[rowb + i];
        int rr = (quad * 4 + i) * 32 + 2 * n;
        *(u32*)&sbuf[wib][0][rr] = pack2(acc[0][i] + dgi * acc[2][i] + bev,
                                         acc[1][i] + dgi * acc[3][i] + bov);
        *(u32*)&sbuf[wib][1][rr] = pack2(acc[4][i], acc[5][i]);
        *(u32*)&sbuf[wib][2][rr] = pack2(acc[6][i], acc[7][i]);
        *(u32*)&sbuf[wib][3][rr] = pack2(acc[8][i], acc[9][i]);
    }
    __asm__ volatile("s_waitcnt lgkmcnt(0)" ::: "memory");   // intra-wave only

    int lr = lane >> 2, ch = (lane & 3) * 8;          // 16 rows x 16-B chunks
    int lo = lr * 32 + ch;
    size_t go = (size_t)(r0 + lr) * 32 + ch;
    *(uint4*)(Self + go) = *(const uint4*)&sbuf[wib][0][lo];
    *(uint4*)(T   + go)  = *(const uint4*)&sbuf[wib][1][lo];
    *(uint4*)(TT  + go)  = *(const uint4*)&sbuf[wib][2][lo];
    *(uint4*)(Aux + go)  = *(const uint4*)&sbuf[wib][3][lo];
}

// Inverted index of dst (200K int atomics); overflow (P~1e-10) falls back
// to f32 atomics into xacc.
__global__ __launch_bounds__(256) void fill_edges(
    const int* __restrict__ dst, int* __restrict__ cnt,
    int* __restrict__ elist, const u16* __restrict__ Yaux,
    float* __restrict__ xacc)
{
    int e = blockIdx.x * 256 + threadIdx.x;
    if (e >= NE) return;
    int d = dst[e];
    int pos = atomicAdd(&cnt[d], 1);
    if (pos < ECAP) {
        elist[(size_t)d * ECAP + pos] = e;
    } else {
        const u16* yr = Yaux + (size_t)e * 32;
        float* px = xacc + (size_t)d * 32;
        for (int f = 0; f < 32; ++f) atomicAdd(px + f, bf2f(yr[f]));
    }
}

// Per-side gather (split for attribution: y-side caps at ~146 us so any
// >=146 us kernel must surface in top-5). Thread per (row, quarter): 8
// features via 16-B gathers, batch-8 staging (R7-proven).
// mode 0 (x): extra = inverted-index pull of Yaux + xacc overflow read.
// mode 1 (y): extra = Aux[pm_pd[r]].
__global__ __launch_bounds__(256) void gather_side(
    const u16* __restrict__ Self, const u16* __restrict__ T,
    const u16* __restrict__ TT,
    const u16* __restrict__ Aux,    // y: Xaux
    const u16* __restrict__ Yaux,   // x: edge rows
    const float* __restrict__ xacc, // x: overflow acc
    const int* __restrict__ cnt, const int* __restrict__ elist,
    const int* __restrict__ t, const int* __restrict__ tt,
    const int* __restrict__ pm_pd,
    u16* __restrict__ pre_h,        // base offset pre-applied by caller
    float* __restrict__ ss,         // [sum(32)|sq(32)]
    int M, int mode)
{
    __shared__ int s_t[1024];
    __shared__ int s_tt[1024];
    __shared__ float s_sum[32];
    __shared__ float s_sq[32];
    if (threadIdx.x < 32) { s_sum[threadIdx.x] = 0.f; s_sq[threadIdx.x] = 0.f; }
    int row0 = blockIdx.x * 64;
    int lim = (M - row0) * 16;
    for (int i = threadIdx.x; i < 1024; i += 256) {
        s_t[i]  = (i < lim) ? t[row0 * 16 + i]  : 0;
        s_tt[i] = (i < lim) ? tt[row0 * 16 + i] : 0;
    }
    __syncthreads();

    int lr = threadIdx.x >> 2, q = threadIdx.x & 3;
    int r = row0 + lr;
    bool act = r < M;
    int rc = act ? r : row0;

    float a[8];
    {
        uint4 u = *(const uint4*)(Self + (size_t)rc * 32 + q * 8);
        unpack2(u.x, a[0], a[1]); unpack2(u.y, a[2], a[3]);
        unpack2(u.z, a[4], a[5]); unpack2(u.w, a[6], a[7]);
    }
    const int* il  = &s_t[lr * 16];
    const int* ill = &s_tt[lr * 16];
#pragma unroll
    for (int batch = 0; batch < 2; ++batch) {
        uint4 g[8];
#pragma unroll
        for (int j = 0; j < 8; ++j)
            g[j] = *(const uint4*)(T + (size_t)il[batch * 8 + j] * 32 + q * 8);
#pragma unroll
        for (int j = 0; j < 8; ++j) {
            float e0, e1, e2, e3, e4, e5, e6, e7;
            unpack2(g[j].x, e0, e1); unpack2(g[j].y, e2, e3);
            unpack2(g[j].z, e4, e5); unpack2(g[j].w, e6, e7);
            a[0] += e0; a[1] += e1; a[2] += e2; a[3] += e3;
            a[4] += e4; a[5] += e5; a[6] += e6; a[7] += e7;
        }
    }
#pragma unroll
    for (int batch = 0; batch < 2; ++batch) {
        uint4 g[8];
#pragma unroll
        for (int j = 0; j < 8; ++j)
            g[j] = *(const uint4*)(TT + (size_t)ill[batch * 8 + j] * 32 + q * 8);
#pragma unroll
        for (int j = 0; j < 8; ++j) {
            float e0, e1, e2, e3, e4, e5, e6, e7;
            unpack2(g[j].x, e0, e1); unpack2(g[j].y, e2, e3);
            unpack2(g[j].z, e4, e5); unpack2(g[j].w, e6, e7);
            a[0] += e0; a[1] += e1; a[2] += e2; a[3] += e3;
            a[4] += e4; a[5] += e5; a[6] += e6; a[7] += e7;
        }
    }
    if (mode == 0) {
        int c = cnt[rc];
        if (c > ECAP) c = ECAP;
        const int* el = elist + (size_t)rc * ECAP;
        for (int k = 0; k < c; ++k) {
            uint4 g = *(const uint4*)(Yaux + (size_t)el[k] * 32 + q * 8);
            float e0, e1, e2, e3, e4, e5, e6, e7;
            unpack2(g.x, e0, e1); unpack2(g.y, e2, e3);
            unpack2(g.z, e4, e5); unpack2(g.w, e6, e7);
            a[0] += e0; a[1] += e1; a[2] += e2; a[3] += e3;
            a[4] += e4; a[5] += e5; a[6] += e6; a[7] += e7;
        }
        float4 b0 = *(const float4*)(xacc + (size_t)rc * 32 + q * 8);
        float4 b1 = *(const float4*)(xacc + (size_t)rc * 32 + q * 8 + 4);
        a[0] += b0.x; a[1] += b0.y; a[2] += b0.z; a[3] += b0.w;
        a[4] += b1.x; a[5] += b1.y; a[6] += b1.z; a[7] += b1.w;
    } else {
        int ai = pm_pd[rc];
        uint4 g = *(const uint4*)(Aux + (size_t)ai * 32 + q * 8);
        float e0, e1, e2, e3, e4, e5, e6, e7;
        unpack2(g.x, e0, e1); unpack2(g.y, e2, e3);
        unpack2(g.z, e4, e5); unpack2(g.w, e6, e7);
        a[0] += e0; a[1] += e1; a[2] += e2; a[3] += e3;
        a[4] += e4; a[5] += e5; a[6] += e6; a[7] += e7;
    }
    if (q >= 2) {
#pragma unroll
        for (int i = 0; i < 8; ++i) a[i] = fmaxf(a[i], 0.f);
    }
    if (act) {
        uint4 o;
        o.x = pack2(a[0], a[1]); o.y = pack2(a[2], a[3]);
        o.z = pack2(a[4], a[5]); o.w = pack2(a[6], a[7]);
        *(uint4*)(pre_h + (size_t)r * 32 + q * 8) = o;
    } else {
#pragma unroll
        for (int i = 0; i < 8; ++i) a[i] = 0.f;
    }
#pragma unroll
    for (int i = 0; i < 8; ++i) {
        atomicAdd(&s_sum[q * 8 + i], a[i]);
        atomicAdd(&s_sq[q * 8 + i], a[i] * a[i]);
    }
    __syncthreads();
    if (threadIdx.x < 32) {
        atomicAdd(&ss[threadIdx.x], s_sum[threadIdx.x]);
        atomicAdd(&ss[32 + threadIdx.x], s_sq[threadIdx.x]);
    }
}

__global__ void finalize_stats(
    const float* stats,
    const float* bnxw, const float* bnxb, const float* bnyw, const float* bnyb,
    float* scsh)
{
    int f = threadIdx.x;
    if (f < 32) {
        float m = stats[f] / (float)NN;
        float var = stats[32 + f] / (float)NN - m * m;
        float inv = rsqrtf(var + 1e-5f);
        float sc = bnxw[f] * inv;
        scsh[f] = sc; scsh[32 + f] = bnxb[f] - m * sc;
    } else if (f < 64) {
        int g = f - 32;
        float m = stats[64 + g] / (float)NE;
        float var = stats[96 + g] / (float)NE - m * m;
        float inv = rsqrtf(var + 1e-5f);
        float sc = bnyw[g] * inv;
        scsh[64 + g] = sc; scsh[96 + g] = bnyb[g] - m * sc;
    }
}

__global__ __launch_bounds__(256) void apply_bn(
    const u16* __restrict__ pre_h, const float* __restrict__ scsh,
    float* __restrict__ out)
{
    int tid = blockIdx.x * 256 + threadIdx.x;   // MT*8 threads, 4 elems each
    if (tid >= MT * 8) return;
    int fq = (tid & 7) * 4;
    const float* sc = (tid < NN * 8) ? scsh : scsh + 64;
    ushort4 u = ((const ushort4*)pre_h)[tid];
    float4 o;
    o.x = bf2f(u.x) * sc[fq + 0] + sc[32 + fq + 0];
    o.y = bf2f(u.y) * sc[fq + 1] + sc[32 + fq + 1];
    o.z = bf2f(u.z) * sc[fq + 2] + sc[32 + fq + 2];
    o.w = bf2f(u.w) * sc[fq + 3] + sc[32 + fq + 3];
    ((float4*)out)[tid] = o;
}

extern "C" void kernel_launch(void* const* d_in, const int* in_sizes, int n_in,
                              void* d_out, int out_size, void* d_ws, size_t ws_size,
                              hipStream_t stream)
{
    const float* x      = (const float*)d_in[0];
    const float* y      = (const float*)d_in[1];
    const float* deg_g  = (const float*)d_in[2];
    const float* deg_lg = (const float*)d_in[3];
    const int* t_g   = (const int*)d_in[4];
    const int* tt_g  = (const int*)d_in[5];
    const int* t_lg  = (const int*)d_in[6];
    const int* tt_lg = (const int*)d_in[7];
    const int* dst   = (const int*)d_in[8];
    const int* pm_pd = (const int*)d_in[9];

    char* ws = (char*)d_ws;
    u16* Bfx   = (u16*)(ws + 256);              // 5120 u16 = 10 KB
    u16* Bfy   = Bfx + 5120;                    // 10 KB
    float* bx  = (float*)(ws + 24576);          // 32 f32
    float* by  = bx + 32;
    float* stats = by + 32;                     // 128 f32
    float* scsh  = stats + 128;                 // 128 f32
    u16* Xself = (u16*)(ws + 65536);            // NN*32 = 6.4 MB each
    u16* Xt    = Xself + (size_t)NN * 32;
    u16* Xtt   = Xt    + (size_t)NN * 32;
    u16* Xaux  = Xtt   + (size_t)NN * 32;
    u16* Yself = Xaux  + (size_t)NN * 32;       // NE*32 = 12.8 MB each
    u16* Yt    = Yself + (size_t)NE * 32;
    u16* Ytt   = Yt    + (size_t)NE * 32;
    u16* Yaux  = Ytt   + (size_t)NE * 32;       // 12.8 MB
    float* xacc = (float*)(Yaux + (size_t)NE * 32);  // NN*32 f32 (overflow acc)
    u16* pre_h = (u16*)(xacc + (size_t)NN * 32);     // MT*32 bf16 = 19.2 MB
    int* cnt   = (int*)(pre_h + (size_t)MT * 32);    // NN int
    int* elist = cnt + NN;                           // NN*ECAP int = 6.4 MB

    hipMemsetAsync(stats, 0, 256 * sizeof(float), stream);
    hipMemsetAsync(xacc, 0, (size_t)NN * 32 * sizeof(float), stream);
    hipMemsetAsync(cnt, 0, (size_t)NN * sizeof(int), stream);

    prep_kernel<<<41, 256, 0, stream>>>(
        (const float*)d_in[10], (const float*)d_in[12], (const float*)d_in[14],
        (const float*)d_in[16], (const float*)d_in[18], (const float*)d_in[20],
        (const float*)d_in[22], (const float*)d_in[24],
        (const float*)d_in[11], (const float*)d_in[13], (const float*)d_in[15],
        (const float*)d_in[17], (const float*)d_in[19], (const float*)d_in[21],
        (const float*)d_in[23], (const float*)d_in[25],
        Bfx, Bfy, bx, by);
    gemm2<<<4688, 256, 0, stream>>>(x, y, Bfx, Bfy, bx, by, deg_g, deg_lg,
                                    Xself, Xt, Xtt, Xaux,
                                    Yself, Yt, Ytt, Yaux);
    fill_edges<<<782, 256, 0, stream>>>(dst, cnt, elist, Yaux, xacc);
    gather_side<<<1563, 256, 0, stream>>>(Xself, Xt, Xtt, nullptr, Yaux, xacc,
                                          cnt, elist, t_g, tt_g, nullptr,
                                          pre_h, stats, NN, 0);
    gather_side<<<3125, 256, 0, stream>>>(Yself, Yt, Ytt, Xaux, nullptr, nullptr,
                                          nullptr, nullptr, t_lg, tt_lg, pm_pd,
                                          pre_h + (size_t)NN * 32, stats + 64,
                                          NE, 1);
    finalize_stats<<<1, 64, 0, stream>>>(stats,
        (const float*)d_in[26], (const float*)d_in[27],
        (const float*)d_in[28], (const float*)d_in[29], scsh);
    apply_bn<<<9375, 256, 0, stream>>>(pre_h, scsh, (float*)d_out);
}